// Round 7
// baseline (313.551 us; speedup 1.0000x reference)
//
#include <hip/hip_runtime.h>
#include <hip/hip_bf16.h>

#define NN 10000
#define NE 160000
#define NET 170000   // edges + self loops
#define IN_DIM 512
#define D1 1024      // HEADS*HID
#define HEADS 4
#define HID 256
#define OUT_DIM 512
#define NEG_SLOPE 0.2f

typedef __attribute__((ext_vector_type(8))) short bf16x8;
typedef __attribute__((ext_vector_type(4))) float f32x4;

__device__ inline float b2f(unsigned short b) {
    union { unsigned u; float f; } x; x.u = ((unsigned)b) << 16; return x.f;
}
__device__ inline unsigned short f2b(float f) {
    union { float f; unsigned u; } x; x.f = f;
    unsigned u = x.u;
    unsigned r = u + 0x7FFFu + ((u >> 16) & 1u);
    return (unsigned short)(r >> 16);
}
__device__ inline float lrelu(float v) { return v > 0.f ? v : NEG_SLOPE * v; }

// ---- init: zero counts/cursor; block 0 detects edge_index dtype
// (int64 -> high words of first 500 values are all 0)
__global__ void init_kernel(const int* ei32, int* flag, int* counts, int* cursor) {
    int i = blockIdx.x * blockDim.x + threadIdx.x;
    if (i < NN) { counts[i] = 0; cursor[i] = 0; }
    if (blockIdx.x == 0) {
        __shared__ int nz;
        if (threadIdx.x == 0) nz = 0;
        __syncthreads();
        int acc = 0;
        for (int k = threadIdx.x; k < 500; k += 256) acc |= ei32[2 * k + 1];
        if (acc) atomicOr(&nz, 1);
        __syncthreads();
        if (threadIdx.x == 0) flag[0] = (nz == 0) ? 1 : 0;
    }
}

__device__ inline void load_edge(const void* ei, int f64, int e, int& s, int& d) {
    if (f64) {
        const long long* p = (const long long*)ei;
        s = (int)p[e]; d = (int)p[NE + e];
    } else {
        const int* p = (const int*)ei;
        s = p[e]; d = p[NE + e];
    }
}

__global__ void count_kernel(const void* ei, const int* flag, int* counts) {
    int e = blockIdx.x * blockDim.x + threadIdx.x;
    if (e >= NET) return;
    int s, d;
    if (e < NE) load_edge(ei, *flag, e, s, d);
    else d = e - NE;
    atomicAdd(&counts[d], 1);
}

__global__ __launch_bounds__(256) void scan_kernel(const int* counts, int* indptr) {
    __shared__ int part[256];
    int t = threadIdx.x;
    int base = t * 40;
    int local[40];
    int sum = 0;
#pragma unroll
    for (int k = 0; k < 40; k++) {
        int i = base + k;
        int c = (i < NN) ? counts[i] : 0;
        local[k] = sum;
        sum += c;
    }
    part[t] = sum;
    __syncthreads();
    for (int off = 1; off < 256; off <<= 1) {
        int v = (t >= off) ? part[t - off] : 0;
        __syncthreads();
        part[t] += v;
        __syncthreads();
    }
    int excl = part[t] - sum;
#pragma unroll
    for (int k = 0; k < 40; k++) {
        int i = base + k;
        if (i < NN) indptr[i] = excl + local[k];
    }
    if (t == 255) indptr[NN] = part[255];
}

__global__ void fill_kernel(const void* ei, const int* flag, const int* indptr,
                            int* cursor, int* csr_src) {
    int e = blockIdx.x * blockDim.x + threadIdx.x;
    if (e >= NET) return;
    int s, d;
    if (e < NE) load_edge(ei, *flag, e, s, d);
    else { s = e - NE; d = s; }
    int pos = indptr[d] + atomicAdd(&cursor[d], 1);
    csr_src[pos] = s;
}

// ---- prep: fused x->bf16 convert + 3 weight transposes (sectioned 1D grid)
__device__ void tpose_tile(const float* __restrict__ in, unsigned short* __restrict__ out,
                           int R, int C, int bx, int by) {
    __shared__ float tile[32][33];
    int tx = threadIdx.x & 31, ty = threadIdx.x >> 5;
    int c = bx * 32 + tx;
#pragma unroll
    for (int r0 = 0; r0 < 32; r0 += 8) {
        int r = by * 32 + ty + r0;
        tile[ty + r0][tx] = in[(size_t)r * C + c];
    }
    __syncthreads();
    int oc = by * 32 + tx;
#pragma unroll
    for (int r0 = 0; r0 < 32; r0 += 8) {
        int orow = bx * 32 + ty + r0;
        out[(size_t)orow * R + oc] = f2b(tile[tx][ty + r0]);
    }
}

#define CVT_NB 5000   // NN*IN_DIM/4/256
#define TP1_NB 512    // (D1/32)*(IN_DIM/32)
#define TP2_NB 1024   // (D1/32)*(D1/32)
#define TP3_NB 512    // (OUT_DIM/32)*(D1/32)
__global__ __launch_bounds__(256) void prep_kernel(
    const float* __restrict__ x, unsigned short* __restrict__ xb,
    const float* __restrict__ W1, unsigned short* __restrict__ W1t,
    const float* __restrict__ W2, unsigned short* __restrict__ W2t,
    const float* __restrict__ fcW, unsigned short* __restrict__ fcWt) {
    int b = blockIdx.x;
    if (b < CVT_NB) {
        int i = b * 256 + threadIdx.x;
        float4 v = reinterpret_cast<const float4*>(x)[i];
        ushort4 o;
        o.x = f2b(v.x); o.y = f2b(v.y); o.z = f2b(v.z); o.w = f2b(v.w);
        reinterpret_cast<ushort4*>(xb)[i] = o;
        return;
    }
    b -= CVT_NB;
    if (b < TP1_NB) { tpose_tile(W1, W1t, IN_DIM, D1, b & 31, b >> 5); return; }
    b -= TP1_NB;
    if (b < TP2_NB) { tpose_tile(W2, W2t, D1, D1, b & 31, b >> 5); return; }
    b -= TP2_NB;
    tpose_tile(fcW, fcWt, D1, OUT_DIM, b & 15, b >> 4);
}

// ---- C[M][N] = A[M][K](bf16) @ B[N][K](bf16)^T
// 128x128 tile, BK=64, 4 waves (2x2 of 64x64), global_load_lds width 16,
// XOR-swizzled LDS (pre-swizzled global source cols, swizzled ds_read),
// bijective XCD-aware block swizzle.
#define BM 128
#define BN 128
#define BK 64
__global__ __launch_bounds__(256) void gemm128(
    const unsigned short* __restrict__ A, const unsigned short* __restrict__ B,
    const float* __restrict__ bias, float* __restrict__ Cf, unsigned short* __restrict__ Cb,
    int M, int N, int K, int NB) {
    __shared__ __align__(16) unsigned short As[BM * BK];  // 16 KB
    __shared__ __align__(16) unsigned short Bs[BN * BK];  // 16 KB
    int t = threadIdx.x;
    int nwg = gridDim.x;
    int q = nwg >> 3, r = nwg & 7;
    int xcd = blockIdx.x & 7, jj = blockIdx.x >> 3;
    int wg = (xcd < r ? xcd * (q + 1) : r * (q + 1) + (xcd - r) * q) + jj;
    int row0 = (wg / NB) * BM, col0 = (wg % NB) * BN;

    int w = t >> 6, l = t & 63;
    int wr = w >> 1, wc = w & 1;
    f32x4 acc[4][4] = {};

    int srow = w * 8 + (l >> 3);                 // row within 32-row issue chunk
    int scs = (((l & 7) ^ (l >> 3)) * 8);        // source col in shorts (inverse swizzle)
    const unsigned short* ap0 = A + (size_t)min(row0 +  0 + srow, M - 1) * K + scs;
    const unsigned short* ap1 = A + (size_t)min(row0 + 32 + srow, M - 1) * K + scs;
    const unsigned short* ap2 = A + (size_t)min(row0 + 64 + srow, M - 1) * K + scs;
    const unsigned short* ap3 = A + (size_t)min(row0 + 96 + srow, M - 1) * K + scs;
    const unsigned short* bp0 = B + (size_t)(col0 +  0 + srow) * K + scs;
    const unsigned short* bp1 = B + (size_t)(col0 + 32 + srow) * K + scs;
    const unsigned short* bp2 = B + (size_t)(col0 + 64 + srow) * K + scs;
    const unsigned short* bp3 = B + (size_t)(col0 + 96 + srow) * K + scs;
    unsigned short* asd0 = As + 0 * 2048 + w * 512;   // wave-uniform LDS dests
    unsigned short* asd1 = As + 1 * 2048 + w * 512;
    unsigned short* asd2 = As + 2 * 2048 + w * 512;
    unsigned short* asd3 = As + 3 * 2048 + w * 512;
    unsigned short* bsd0 = Bs + 0 * 2048 + w * 512;
    unsigned short* bsd1 = Bs + 1 * 2048 + w * 512;
    unsigned short* bsd2 = Bs + 2 * 2048 + w * 512;
    unsigned short* bsd3 = Bs + 3 * 2048 + w * 512;

    int rr = l & 15;
    int rb = (rr & 7) << 4;          // per-row byte XOR for ds_read
    int kb0 = (l >> 4) << 4;         // 0,16,32,48 byte within K-slice
    const char* Ab = (const char*)As;
    const char* Bb = (const char*)Bs;

#define GLD(src, dst) __builtin_amdgcn_global_load_lds( \
        (const __attribute__((address_space(1))) void*)(src), \
        (__attribute__((address_space(3))) void*)(dst), 16, 0, 0)

    for (int k0 = 0; k0 < K; k0 += BK) {
        GLD(ap0, asd0); GLD(ap1, asd1); GLD(ap2, asd2); GLD(ap3, asd3);
        GLD(bp0, bsd0); GLD(bp1, bsd1); GLD(bp2, bsd2); GLD(bp3, bsd3);
        ap0 += BK; ap1 += BK; ap2 += BK; ap3 += BK;
        bp0 += BK; bp1 += BK; bp2 += BK; bp3 += BK;
        __syncthreads();

#pragma unroll
        for (int ks = 0; ks < 2; ks++) {
            int kb = ((ks << 6) | kb0) ^ rb;
            bf16x8 af[4], bfv[4];
#pragma unroll
            for (int mi = 0; mi < 4; mi++)
                af[mi] = *reinterpret_cast<const bf16x8*>(
                    Ab + (wr * 64 + mi * 16 + rr) * 128 + kb);
#pragma unroll
            for (int ni = 0; ni < 4; ni++)
                bfv[ni] = *reinterpret_cast<const bf16x8*>(
                    Bb + (wc * 64 + ni * 16 + rr) * 128 + kb);
#pragma unroll
            for (int mi = 0; mi < 4; mi++)
#pragma unroll
                for (int ni = 0; ni < 4; ni++)
                    acc[mi][ni] = __builtin_amdgcn_mfma_f32_16x16x32_bf16(
                        af[mi], bfv[ni], acc[mi][ni], 0, 0, 0);
        }
        __syncthreads();
    }
#undef GLD

    // C/D: col = lane&15, row = (lane>>4)*4 + j
    int c_l = l & 15, r_h = (l >> 4) * 4;
#pragma unroll
    for (int mi = 0; mi < 4; mi++)
#pragma unroll
        for (int ni = 0; ni < 4; ni++) {
            int gc = col0 + wc * 64 + ni * 16 + c_l;
#pragma unroll
            for (int j = 0; j < 4; j++) {
                int gr = row0 + wr * 64 + mi * 16 + r_h + j;
                if (gr < M) {
                    float v = acc[mi][ni][j];
                    if (bias) v += bias[gc];
                    if (Cf) Cf[(size_t)gr * N + gc] = v;
                    if (Cb) Cb[(size_t)gr * N + gc] = f2b(v);
                }
            }
        }
}

// ---- a_src/a_dst dots: wave-per-node. Lane l: head l>>4, 16 channels.
// 4-step shuffle reduce over the 16 lanes of each head.
__global__ __launch_bounds__(256) void att_kernel(const unsigned short* __restrict__ hb,
                                                  const float* __restrict__ att_s,
                                                  const float* __restrict__ att_d,
                                                  float* __restrict__ aS, float* __restrict__ aD) {
    int node = blockIdx.x * 4 + (threadIdx.x >> 6);
    int l = threadIdx.x & 63;
    int head = l >> 4, qq = l & 15;
    const unsigned short* hrow = hb + (size_t)node * D1 + head * HID + qq * 16;
    bf16x8 h0 = *reinterpret_cast<const bf16x8*>(hrow);
    bf16x8 h1 = *reinterpret_cast<const bf16x8*>(hrow + 8);
    const float* asp = att_s + head * HID + qq * 16;
    const float* adp = att_d + head * HID + qq * 16;
    float ps = 0.f, pd = 0.f;
#pragma unroll
    for (int c = 0; c < 8; c++) {
        float hv = b2f((unsigned short)h0[c]);
        float hw = b2f((unsigned short)h1[c]);
        ps += hv * asp[c] + hw * asp[8 + c];
        pd += hv * adp[c] + hw * adp[8 + c];
    }
#pragma unroll
    for (int off = 1; off <= 8; off <<= 1) {
        ps += __shfl_xor(ps, off);
        pd += __shfl_xor(pd, off);
    }
    if (qq == 0) {
        aS[node * HEADS + head] = ps;
        aD[node * HEADS + head] = pd;
    }
}

// ---- aggregation: COLUMN-SLICED wave-per-(node,slice), barrier-free, no LDS.
// slice = blockIdx & 7 -> (empirical round-robin) each XCD touches only its
// 128-channel slice of hb (2.56 MB, L2-resident) => ~5x less L2-fill traffic.
// Lane l owns channels slice*128 + 2l (+1); head = slice>>1 (uniform).
// Every lane redundantly computes sum(e); deferred normalization.
__global__ __launch_bounds__(256) void agg_kernel(const unsigned short* __restrict__ hb,
                                                  const float* __restrict__ aS,
                                                  const float* __restrict__ aD,
                                                  const int* __restrict__ indptr,
                                                  const int* __restrict__ csr_src,
                                                  const float* __restrict__ bias,
                                                  unsigned short* __restrict__ outb) {
    int slice = blockIdx.x & 7;
    int node = (blockIdx.x >> 3) * 4 + (threadIdx.x >> 6);
    int l = threadIdx.x & 63;
    int head = slice >> 1;
    int cbase = slice * 128 + l * 2;
    int beg = indptr[node];
    int deg = indptr[node + 1] - beg;
    float adst = aD[node * HEADS + head];
    const int* cs = csr_src + beg;
    const unsigned short* hp = hb + cbase;
    const float* aSh = aS + head;
    float acc0 = 0.f, acc1 = 0.f, esum = 0.f;
    int dm = deg - 1;
    for (int j = 0; j < deg; j += 8) {
        int i1 = min(j + 1, dm), i2 = min(j + 2, dm), i3 = min(j + 3, dm);
        int i4 = min(j + 4, dm), i5 = min(j + 5, dm), i6 = min(j + 6, dm), i7 = min(j + 7, dm);
        int s0 = cs[j],  s1 = cs[i1], s2 = cs[i2], s3 = cs[i3];
        int s4 = cs[i4], s5 = cs[i5], s6 = cs[i6], s7 = cs[i7];
        unsigned r0 = *reinterpret_cast<const unsigned*>(hp + (size_t)s0 * D1);
        unsigned r1 = *reinterpret_cast<const unsigned*>(hp + (size_t)s1 * D1);
        unsigned r2 = *reinterpret_cast<const unsigned*>(hp + (size_t)s2 * D1);
        unsigned r3 = *reinterpret_cast<const unsigned*>(hp + (size_t)s3 * D1);
        unsigned r4 = *reinterpret_cast<const unsigned*>(hp + (size_t)s4 * D1);
        unsigned r5 = *reinterpret_cast<const unsigned*>(hp + (size_t)s5 * D1);
        unsigned r6 = *reinterpret_cast<const unsigned*>(hp + (size_t)s6 * D1);
        unsigned r7 = *reinterpret_cast<const unsigned*>(hp + (size_t)s7 * D1);
        float e0 = __expf(lrelu(aSh[s0 * HEADS] + adst));
        float e1 = (j + 1 <= dm) ? __expf(lrelu(aSh[s1 * HEADS] + adst)) : 0.f;
        float e2 = (j + 2 <= dm) ? __expf(lrelu(aSh[s2 * HEADS] + adst)) : 0.f;
        float e3 = (j + 3 <= dm) ? __expf(lrelu(aSh[s3 * HEADS] + adst)) : 0.f;
        float e4 = (j + 4 <= dm) ? __expf(lrelu(aSh[s4 * HEADS] + adst)) : 0.f;
        float e5 = (j + 5 <= dm) ? __expf(lrelu(aSh[s5 * HEADS] + adst)) : 0.f;
        float e6 = (j + 6 <= dm) ? __expf(lrelu(aSh[s6 * HEADS] + adst)) : 0.f;
        float e7 = (j + 7 <= dm) ? __expf(lrelu(aSh[s7 * HEADS] + adst)) : 0.f;
        esum += (e0 + e1 + e2 + e3) + (e4 + e5 + e6 + e7);
        acc0 += e0 * b2f((unsigned short)(r0 & 0xFFFF)) + e1 * b2f((unsigned short)(r1 & 0xFFFF))
              + e2 * b2f((unsigned short)(r2 & 0xFFFF)) + e3 * b2f((unsigned short)(r3 & 0xFFFF))
              + e4 * b2f((unsigned short)(r4 & 0xFFFF)) + e5 * b2f((unsigned short)(r5 & 0xFFFF))
              + e6 * b2f((unsigned short)(r6 & 0xFFFF)) + e7 * b2f((unsigned short)(r7 & 0xFFFF));
        acc1 += e0 * b2f((unsigned short)(r0 >> 16)) + e1 * b2f((unsigned short)(r1 >> 16))
              + e2 * b2f((unsigned short)(r2 >> 16)) + e3 * b2f((unsigned short)(r3 >> 16))
              + e4 * b2f((unsigned short)(r4 >> 16)) + e5 * b2f((unsigned short)(r5 >> 16))
              + e6 * b2f((unsigned short)(r6 >> 16)) + e7 * b2f((unsigned short)(r7 >> 16));
    }
    float inv = 1.f / (esum + 1e-16f);
    ushort2 o;
    o.x = f2b(fmaxf(acc0 * inv + bias[cbase], 0.f));
    o.y = f2b(fmaxf(acc1 * inv + bias[cbase + 1], 0.f));
    *reinterpret_cast<ushort2*>(outb + (size_t)node * D1 + cbase) = o;
}

extern "C" void kernel_launch(void* const* d_in, const int* in_sizes, int n_in,
                              void* d_out, int out_size, void* d_ws, size_t ws_size,
                              hipStream_t stream) {
    const float* x   = (const float*)d_in[0];
    const void*  ei  = d_in[1];
    const float* W1  = (const float*)d_in[2];
    const float* as1 = (const float*)d_in[3];
    const float* ad1 = (const float*)d_in[4];
    const float* b1  = (const float*)d_in[5];
    const float* W2  = (const float*)d_in[6];
    const float* as2 = (const float*)d_in[7];
    const float* ad2 = (const float*)d_in[8];
    const float* b2  = (const float*)d_in[9];
    const float* fcW = (const float*)d_in[10];
    const float* fcb = (const float*)d_in[11];
    float* out = (float*)d_out;

    char* ws = (char*)d_ws;
    size_t o = 0;
    auto carve = [&](size_t bytes) -> char* {
        char* p = ws + o;
        o = (o + bytes + 255) & ~(size_t)255;
        return p;
    };
    unsigned short* xb   = (unsigned short*)carve((size_t)NN * IN_DIM * 2);
    unsigned short* hb   = (unsigned short*)carve((size_t)NN * D1 * 2);
    unsigned short* x2b  = (unsigned short*)carve((size_t)NN * D1 * 2);
    unsigned short* W1t  = (unsigned short*)carve((size_t)D1 * IN_DIM * 2);
    unsigned short* W2t  = (unsigned short*)carve((size_t)D1 * D1 * 2);
    unsigned short* fcWt = (unsigned short*)carve((size_t)OUT_DIM * D1 * 2);
    float* aS   = (float*)carve((size_t)NN * HEADS * 4);
    float* aD   = (float*)carve((size_t)NN * HEADS * 4);
    int* counts = (int*)carve((size_t)NN * 4);
    int* cursor = (int*)carve((size_t)NN * 4);
    int* indptr = (int*)carve((size_t)(NN + 1) * 4);
    int* csr_src= (int*)carve((size_t)NET * 4);
    int* flag   = (int*)carve(4);
    (void)ws_size; (void)in_sizes; (void)n_in; (void)out_size;

    // CSR build (dtype-agnostic edge loads)
    init_kernel<<<(NN + 255) / 256, 256, 0, stream>>>((const int*)ei, flag, counts, cursor);
    count_kernel<<<(NET + 255) / 256, 256, 0, stream>>>(ei, flag, counts);
    scan_kernel<<<1, 256, 0, stream>>>(counts, indptr);
    fill_kernel<<<(NET + 255) / 256, 256, 0, stream>>>(ei, flag, indptr, cursor, csr_src);

    // fused conversions (cvt + 3 transposes)
    prep_kernel<<<CVT_NB + TP1_NB + TP2_NB + TP3_NB, 256, 0, stream>>>(
        x, xb, W1, W1t, W2, W2t, fcW, fcWt);

    const int MB = (NN + BM - 1) / BM;  // 79
    // layer 1
    gemm128<<<MB * (D1 / BN), 256, 0, stream>>>(xb, W1t, nullptr, nullptr, hb,
                                                NN, D1, IN_DIM, D1 / BN);
    att_kernel<<<NN / 4, 256, 0, stream>>>(hb, as1, ad1, aS, aD);
    agg_kernel<<<(NN / 4) * 8, 256, 0, stream>>>(hb, aS, aD, indptr, csr_src, b1, x2b);
    // layer 2
    gemm128<<<MB * (D1 / BN), 256, 0, stream>>>(x2b, W2t, nullptr, nullptr, hb,
                                                NN, D1, D1, D1 / BN);
    att_kernel<<<NN / 4, 256, 0, stream>>>(hb, as2, ad2, aS, aD);
    agg_kernel<<<(NN / 4) * 8, 256, 0, stream>>>(hb, aS, aD, indptr, csr_src, b2, x2b);
    // final fc (bias, f32 out)
    gemm128<<<MB * (OUT_DIM / BN), 256, 0, stream>>>(x2b, fcWt, fcb, out, nullptr,
                                                     NN, OUT_DIM, D1, OUT_DIM / BN);
}

// Round 8
// 279.637 us; speedup vs baseline: 1.1213x; 1.1213x over previous
//
#include <hip/hip_runtime.h>
#include <hip/hip_bf16.h>

#define NN 10000
#define NE 160000
#define NET 170000   // edges + self loops
#define IN_DIM 512
#define D1 1024      // HEADS*HID
#define HEADS 4
#define HID 256
#define OUT_DIM 512
#define NEG_SLOPE 0.2f

typedef __attribute__((ext_vector_type(8))) short bf16x8;
typedef __attribute__((ext_vector_type(4))) float f32x4;

__device__ inline float b2f(unsigned short b) {
    union { unsigned u; float f; } x; x.u = ((unsigned)b) << 16; return x.f;
}
__device__ inline unsigned short f2b(float f) {
    union { float f; unsigned u; } x; x.f = f;
    unsigned u = x.u;
    unsigned r = u + 0x7FFFu + ((u >> 16) & 1u);
    return (unsigned short)(r >> 16);
}
__device__ inline float lrelu(float v) { return v > 0.f ? v : NEG_SLOPE * v; }

// ---- init: zero counts/cursor; block 0 detects edge_index dtype
// (int64 -> high words of first 500 values are all 0)
__global__ void init_kernel(const int* ei32, int* flag, int* counts, int* cursor) {
    int i = blockIdx.x * blockDim.x + threadIdx.x;
    if (i < NN) { counts[i] = 0; cursor[i] = 0; }
    if (blockIdx.x == 0) {
        __shared__ int nz;
        if (threadIdx.x == 0) nz = 0;
        __syncthreads();
        int acc = 0;
        for (int k = threadIdx.x; k < 500; k += 256) acc |= ei32[2 * k + 1];
        if (acc) atomicOr(&nz, 1);
        __syncthreads();
        if (threadIdx.x == 0) flag[0] = (nz == 0) ? 1 : 0;
    }
}

__device__ inline void load_edge(const void* ei, int f64, int e, int& s, int& d) {
    if (f64) {
        const long long* p = (const long long*)ei;
        s = (int)p[e]; d = (int)p[NE + e];
    } else {
        const int* p = (const int*)ei;
        s = p[e]; d = p[NE + e];
    }
}

__global__ void count_kernel(const void* ei, const int* flag, int* counts) {
    int e = blockIdx.x * blockDim.x + threadIdx.x;
    if (e >= NET) return;
    int s, d;
    if (e < NE) load_edge(ei, *flag, e, s, d);
    else d = e - NE;
    atomicAdd(&counts[d], 1);
}

__global__ __launch_bounds__(256) void scan_kernel(const int* counts, int* indptr) {
    __shared__ int part[256];
    int t = threadIdx.x;
    int base = t * 40;
    int local[40];
    int sum = 0;
#pragma unroll
    for (int k = 0; k < 40; k++) {
        int i = base + k;
        int c = (i < NN) ? counts[i] : 0;
        local[k] = sum;
        sum += c;
    }
    part[t] = sum;
    __syncthreads();
    for (int off = 1; off < 256; off <<= 1) {
        int v = (t >= off) ? part[t - off] : 0;
        __syncthreads();
        part[t] += v;
        __syncthreads();
    }
    int excl = part[t] - sum;
#pragma unroll
    for (int k = 0; k < 40; k++) {
        int i = base + k;
        if (i < NN) indptr[i] = excl + local[k];
    }
    if (t == 255) indptr[NN] = part[255];
}

__global__ void fill_kernel(const void* ei, const int* flag, const int* indptr,
                            int* cursor, int* csr_src) {
    int e = blockIdx.x * blockDim.x + threadIdx.x;
    if (e >= NET) return;
    int s, d;
    if (e < NE) load_edge(ei, *flag, e, s, d);
    else { s = e - NE; d = s; }
    int pos = indptr[d] + atomicAdd(&cursor[d], 1);
    csr_src[pos] = s;
}

// ---- prep: fused x->bf16 convert + 3 weight transposes (sectioned 1D grid)
__device__ void tpose_tile(const float* __restrict__ in, unsigned short* __restrict__ out,
                           int R, int C, int bx, int by) {
    __shared__ float tile[32][33];
    int tx = threadIdx.x & 31, ty = threadIdx.x >> 5;
    int c = bx * 32 + tx;
#pragma unroll
    for (int r0 = 0; r0 < 32; r0 += 8) {
        int r = by * 32 + ty + r0;
        tile[ty + r0][tx] = in[(size_t)r * C + c];
    }
    __syncthreads();
    int oc = by * 32 + tx;
#pragma unroll
    for (int r0 = 0; r0 < 32; r0 += 8) {
        int orow = bx * 32 + ty + r0;
        out[(size_t)orow * R + oc] = f2b(tile[tx][ty + r0]);
    }
}

#define CVT_NB 5000   // NN*IN_DIM/4/256
#define TP1_NB 512    // (D1/32)*(IN_DIM/32)
#define TP2_NB 1024   // (D1/32)*(D1/32)
#define TP3_NB 512    // (OUT_DIM/32)*(D1/32)
__global__ __launch_bounds__(256) void prep_kernel(
    const float* __restrict__ x, unsigned short* __restrict__ xb,
    const float* __restrict__ W1, unsigned short* __restrict__ W1t,
    const float* __restrict__ W2, unsigned short* __restrict__ W2t,
    const float* __restrict__ fcW, unsigned short* __restrict__ fcWt) {
    int b = blockIdx.x;
    if (b < CVT_NB) {
        int i = b * 256 + threadIdx.x;
        float4 v = reinterpret_cast<const float4*>(x)[i];
        ushort4 o;
        o.x = f2b(v.x); o.y = f2b(v.y); o.z = f2b(v.z); o.w = f2b(v.w);
        reinterpret_cast<ushort4*>(xb)[i] = o;
        return;
    }
    b -= CVT_NB;
    if (b < TP1_NB) { tpose_tile(W1, W1t, IN_DIM, D1, b & 31, b >> 5); return; }
    b -= TP1_NB;
    if (b < TP2_NB) { tpose_tile(W2, W2t, D1, D1, b & 31, b >> 5); return; }
    b -= TP2_NB;
    tpose_tile(fcW, fcWt, D1, OUT_DIM, b & 15, b >> 4);
}

// ---- C[M][N] = A[M][K](bf16) @ B[N][K](bf16)^T
// 128x128 tile, BK=64, 4 waves (2x2 of 64x64), global_load_lds width 16,
// XOR-swizzled LDS (pre-swizzled global source cols, swizzled ds_read),
// bijective XCD-aware block swizzle.
#define BM 128
#define BN 128
#define BK 64
__global__ __launch_bounds__(256) void gemm128(
    const unsigned short* __restrict__ A, const unsigned short* __restrict__ B,
    const float* __restrict__ bias, float* __restrict__ Cf, unsigned short* __restrict__ Cb,
    int M, int N, int K, int NB) {
    __shared__ __align__(16) unsigned short As[BM * BK];  // 16 KB
    __shared__ __align__(16) unsigned short Bs[BN * BK];  // 16 KB
    int t = threadIdx.x;
    int nwg = gridDim.x;
    int q = nwg >> 3, r = nwg & 7;
    int xcd = blockIdx.x & 7, jj = blockIdx.x >> 3;
    int wg = (xcd < r ? xcd * (q + 1) : r * (q + 1) + (xcd - r) * q) + jj;
    int row0 = (wg / NB) * BM, col0 = (wg % NB) * BN;

    int w = t >> 6, l = t & 63;
    int wr = w >> 1, wc = w & 1;
    f32x4 acc[4][4] = {};

    int srow = w * 8 + (l >> 3);                 // row within 32-row issue chunk
    int scs = (((l & 7) ^ (l >> 3)) * 8);        // source col in shorts (inverse swizzle)
    const unsigned short* ap0 = A + (size_t)min(row0 +  0 + srow, M - 1) * K + scs;
    const unsigned short* ap1 = A + (size_t)min(row0 + 32 + srow, M - 1) * K + scs;
    const unsigned short* ap2 = A + (size_t)min(row0 + 64 + srow, M - 1) * K + scs;
    const unsigned short* ap3 = A + (size_t)min(row0 + 96 + srow, M - 1) * K + scs;
    const unsigned short* bp0 = B + (size_t)(col0 +  0 + srow) * K + scs;
    const unsigned short* bp1 = B + (size_t)(col0 + 32 + srow) * K + scs;
    const unsigned short* bp2 = B + (size_t)(col0 + 64 + srow) * K + scs;
    const unsigned short* bp3 = B + (size_t)(col0 + 96 + srow) * K + scs;
    unsigned short* asd0 = As + 0 * 2048 + w * 512;   // wave-uniform LDS dests
    unsigned short* asd1 = As + 1 * 2048 + w * 512;
    unsigned short* asd2 = As + 2 * 2048 + w * 512;
    unsigned short* asd3 = As + 3 * 2048 + w * 512;
    unsigned short* bsd0 = Bs + 0 * 2048 + w * 512;
    unsigned short* bsd1 = Bs + 1 * 2048 + w * 512;
    unsigned short* bsd2 = Bs + 2 * 2048 + w * 512;
    unsigned short* bsd3 = Bs + 3 * 2048 + w * 512;

    int rr = l & 15;
    int rb = (rr & 7) << 4;          // per-row byte XOR for ds_read
    int kb0 = (l >> 4) << 4;         // 0,16,32,48 byte within K-slice
    const char* Ab = (const char*)As;
    const char* Bb = (const char*)Bs;

#define GLD(src, dst) __builtin_amdgcn_global_load_lds( \
        (const __attribute__((address_space(1))) void*)(src), \
        (__attribute__((address_space(3))) void*)(dst), 16, 0, 0)

    for (int k0 = 0; k0 < K; k0 += BK) {
        GLD(ap0, asd0); GLD(ap1, asd1); GLD(ap2, asd2); GLD(ap3, asd3);
        GLD(bp0, bsd0); GLD(bp1, bsd1); GLD(bp2, bsd2); GLD(bp3, bsd3);
        ap0 += BK; ap1 += BK; ap2 += BK; ap3 += BK;
        bp0 += BK; bp1 += BK; bp2 += BK; bp3 += BK;
        __syncthreads();

#pragma unroll
        for (int ks = 0; ks < 2; ks++) {
            int kb = ((ks << 6) | kb0) ^ rb;
            bf16x8 af[4], bfv[4];
#pragma unroll
            for (int mi = 0; mi < 4; mi++)
                af[mi] = *reinterpret_cast<const bf16x8*>(
                    Ab + (wr * 64 + mi * 16 + rr) * 128 + kb);
#pragma unroll
            for (int ni = 0; ni < 4; ni++)
                bfv[ni] = *reinterpret_cast<const bf16x8*>(
                    Bb + (wc * 64 + ni * 16 + rr) * 128 + kb);
#pragma unroll
            for (int mi = 0; mi < 4; mi++)
#pragma unroll
                for (int ni = 0; ni < 4; ni++)
                    acc[mi][ni] = __builtin_amdgcn_mfma_f32_16x16x32_bf16(
                        af[mi], bfv[ni], acc[mi][ni], 0, 0, 0);
        }
        __syncthreads();
    }
#undef GLD

    // C/D: col = lane&15, row = (lane>>4)*4 + j
    int c_l = l & 15, r_h = (l >> 4) * 4;
#pragma unroll
    for (int mi = 0; mi < 4; mi++)
#pragma unroll
        for (int ni = 0; ni < 4; ni++) {
            int gc = col0 + wc * 64 + ni * 16 + c_l;
#pragma unroll
            for (int j = 0; j < 4; j++) {
                int gr = row0 + wr * 64 + mi * 16 + r_h + j;
                if (gr < M) {
                    float v = acc[mi][ni][j];
                    if (bias) v += bias[gc];
                    if (Cf) Cf[(size_t)gr * N + gc] = v;
                    if (Cb) Cb[(size_t)gr * N + gc] = f2b(v);
                }
            }
        }
}

// ---- a_src/a_dst dots: wave-per-node. Lane l: head l>>4, 16 channels.
__global__ __launch_bounds__(256) void att_kernel(const unsigned short* __restrict__ hb,
                                                  const float* __restrict__ att_s,
                                                  const float* __restrict__ att_d,
                                                  float* __restrict__ aS, float* __restrict__ aD) {
    int node = blockIdx.x * 4 + (threadIdx.x >> 6);
    int l = threadIdx.x & 63;
    int head = l >> 4, qq = l & 15;
    const unsigned short* hrow = hb + (size_t)node * D1 + head * HID + qq * 16;
    bf16x8 h0 = *reinterpret_cast<const bf16x8*>(hrow);
    bf16x8 h1 = *reinterpret_cast<const bf16x8*>(hrow + 8);
    const float* asp = att_s + head * HID + qq * 16;
    const float* adp = att_d + head * HID + qq * 16;
    float ps = 0.f, pd = 0.f;
#pragma unroll
    for (int c = 0; c < 8; c++) {
        float hv = b2f((unsigned short)h0[c]);
        float hw = b2f((unsigned short)h1[c]);
        ps += hv * asp[c] + hw * asp[8 + c];
        pd += hv * adp[c] + hw * adp[8 + c];
    }
#pragma unroll
    for (int off = 1; off <= 8; off <<= 1) {
        ps += __shfl_xor(ps, off);
        pd += __shfl_xor(pd, off);
    }
    if (qq == 0) {
        aS[node * HEADS + head] = ps;
        aD[node * HEADS + head] = pd;
    }
}

// ---- alpha precompute: wave-per-node. Lane l handles edges l, l+64, ...
// Computes unnormalized e per (edge, head), stores HEAD-MAJOR alpha[h][E]
// (coalesced in j), and einv[node][h] = 1/sum(e).
__global__ __launch_bounds__(256) void alpha_kernel(
    const float* __restrict__ aS, const float* __restrict__ aD,
    const int* __restrict__ indptr, const int* __restrict__ csr_src,
    float* __restrict__ alpha, float* __restrict__ einv) {
    int node = blockIdx.x * 4 + (threadIdx.x >> 6);
    int l = threadIdx.x & 63;
    int beg = indptr[node], deg = indptr[node + 1] - beg;
    float4 ad = *reinterpret_cast<const float4*>(aD + node * HEADS);
    float s0 = 0.f, s1 = 0.f, s2 = 0.f, s3 = 0.f;
    for (int j = l; j < deg; j += 64) {
        int s = csr_src[beg + j];
        float4 a = *reinterpret_cast<const float4*>(aS + s * HEADS);
        float e0 = __expf(lrelu(a.x + ad.x));
        float e1 = __expf(lrelu(a.y + ad.y));
        float e2 = __expf(lrelu(a.z + ad.z));
        float e3 = __expf(lrelu(a.w + ad.w));
        alpha[0 * NET + beg + j] = e0;
        alpha[1 * NET + beg + j] = e1;
        alpha[2 * NET + beg + j] = e2;
        alpha[3 * NET + beg + j] = e3;
        s0 += e0; s1 += e1; s2 += e2; s3 += e3;
    }
#pragma unroll
    for (int off = 32; off; off >>= 1) {
        s0 += __shfl_xor(s0, off);
        s1 += __shfl_xor(s1, off);
        s2 += __shfl_xor(s2, off);
        s3 += __shfl_xor(s3, off);
    }
    if (l == 0) {
        float4 iv;
        iv.x = 1.f / (s0 + 1e-16f);
        iv.y = 1.f / (s1 + 1e-16f);
        iv.z = 1.f / (s2 + 1e-16f);
        iv.w = 1.f / (s3 + 1e-16f);
        *reinterpret_cast<float4*>(einv + node * HEADS) = iv;
    }
}

// ---- aggregation: COLUMN-SLICED wave-per-(node,slice), barrier-free, no LDS.
// slice = blockIdx & 7 (round-robin XCD locality: hb slice = 2.56 MB, L2-fit).
// Per edge: wave-uniform cs/alpha loads (node forced to SGPR via readfirstlane)
// + one contiguous 256B wave gather (4B/lane) + 2 FMA/lane. Softmax weights
// precomputed by alpha_kernel; normalization deferred via einv.
__global__ __launch_bounds__(256) void agg_kernel(const unsigned short* __restrict__ hb,
                                                  const float* __restrict__ alpha,
                                                  const float* __restrict__ einv,
                                                  const int* __restrict__ indptr,
                                                  const int* __restrict__ csr_src,
                                                  const float* __restrict__ bias,
                                                  unsigned short* __restrict__ outb) {
    int slice = blockIdx.x & 7;
    int node = __builtin_amdgcn_readfirstlane((blockIdx.x >> 3) * 4 + (threadIdx.x >> 6));
    int l = threadIdx.x & 63;
    int head = slice >> 1;
    int cbase = slice * 128 + l * 2;
    int beg = indptr[node];
    int deg = indptr[node + 1] - beg;
    const int* cs = csr_src + beg;
    const float* ap = alpha + head * NET + beg;
    const unsigned short* hp = hb + cbase;
    float acc0 = 0.f, acc1 = 0.f;
    int dm = deg - 1;
    for (int j = 0; j < deg; j += 8) {
        int i1 = min(j + 1, dm), i2 = min(j + 2, dm), i3 = min(j + 3, dm);
        int i4 = min(j + 4, dm), i5 = min(j + 5, dm), i6 = min(j + 6, dm), i7 = min(j + 7, dm);
        int s0 = cs[j],  s1 = cs[i1], s2 = cs[i2], s3 = cs[i3];
        int s4 = cs[i4], s5 = cs[i5], s6 = cs[i6], s7 = cs[i7];
        float a0 = ap[j];
        float a1 = (j + 1 <= dm) ? ap[i1] : 0.f;
        float a2 = (j + 2 <= dm) ? ap[i2] : 0.f;
        float a3 = (j + 3 <= dm) ? ap[i3] : 0.f;
        float a4 = (j + 4 <= dm) ? ap[i4] : 0.f;
        float a5 = (j + 5 <= dm) ? ap[i5] : 0.f;
        float a6 = (j + 6 <= dm) ? ap[i6] : 0.f;
        float a7 = (j + 7 <= dm) ? ap[i7] : 0.f;
        unsigned r0 = *reinterpret_cast<const unsigned*>(hp + (size_t)s0 * D1);
        unsigned r1 = *reinterpret_cast<const unsigned*>(hp + (size_t)s1 * D1);
        unsigned r2 = *reinterpret_cast<const unsigned*>(hp + (size_t)s2 * D1);
        unsigned r3 = *reinterpret_cast<const unsigned*>(hp + (size_t)s3 * D1);
        unsigned r4 = *reinterpret_cast<const unsigned*>(hp + (size_t)s4 * D1);
        unsigned r5 = *reinterpret_cast<const unsigned*>(hp + (size_t)s5 * D1);
        unsigned r6 = *reinterpret_cast<const unsigned*>(hp + (size_t)s6 * D1);
        unsigned r7 = *reinterpret_cast<const unsigned*>(hp + (size_t)s7 * D1);
        acc0 += a0 * b2f((unsigned short)(r0 & 0xFFFF)) + a1 * b2f((unsigned short)(r1 & 0xFFFF))
              + a2 * b2f((unsigned short)(r2 & 0xFFFF)) + a3 * b2f((unsigned short)(r3 & 0xFFFF))
              + a4 * b2f((unsigned short)(r4 & 0xFFFF)) + a5 * b2f((unsigned short)(r5 & 0xFFFF))
              + a6 * b2f((unsigned short)(r6 & 0xFFFF)) + a7 * b2f((unsigned short)(r7 & 0xFFFF));
        acc1 += a0 * b2f((unsigned short)(r0 >> 16)) + a1 * b2f((unsigned short)(r1 >> 16))
              + a2 * b2f((unsigned short)(r2 >> 16)) + a3 * b2f((unsigned short)(r3 >> 16))
              + a4 * b2f((unsigned short)(r4 >> 16)) + a5 * b2f((unsigned short)(r5 >> 16))
              + a6 * b2f((unsigned short)(r6 >> 16)) + a7 * b2f((unsigned short)(r7 >> 16));
    }
    float inv = einv[node * HEADS + head];
    ushort2 o;
    o.x = f2b(fmaxf(acc0 * inv + bias[cbase], 0.f));
    o.y = f2b(fmaxf(acc1 * inv + bias[cbase + 1], 0.f));
    *reinterpret_cast<ushort2*>(outb + (size_t)node * D1 + cbase) = o;
}

extern "C" void kernel_launch(void* const* d_in, const int* in_sizes, int n_in,
                              void* d_out, int out_size, void* d_ws, size_t ws_size,
                              hipStream_t stream) {
    const float* x   = (const float*)d_in[0];
    const void*  ei  = d_in[1];
    const float* W1  = (const float*)d_in[2];
    const float* as1 = (const float*)d_in[3];
    const float* ad1 = (const float*)d_in[4];
    const float* b1  = (const float*)d_in[5];
    const float* W2  = (const float*)d_in[6];
    const float* as2 = (const float*)d_in[7];
    const float* ad2 = (const float*)d_in[8];
    const float* b2  = (const float*)d_in[9];
    const float* fcW = (const float*)d_in[10];
    const float* fcb = (const float*)d_in[11];
    float* out = (float*)d_out;

    char* ws = (char*)d_ws;
    size_t o = 0;
    auto carve = [&](size_t bytes) -> char* {
        char* p = ws + o;
        o = (o + bytes + 255) & ~(size_t)255;
        return p;
    };
    unsigned short* xb   = (unsigned short*)carve((size_t)NN * IN_DIM * 2);
    unsigned short* hb   = (unsigned short*)carve((size_t)NN * D1 * 2);
    unsigned short* x2b  = (unsigned short*)carve((size_t)NN * D1 * 2);
    unsigned short* W1t  = (unsigned short*)carve((size_t)D1 * IN_DIM * 2);
    unsigned short* W2t  = (unsigned short*)carve((size_t)D1 * D1 * 2);
    unsigned short* fcWt = (unsigned short*)carve((size_t)OUT_DIM * D1 * 2);
    float* aS    = (float*)carve((size_t)NN * HEADS * 4);
    float* aD    = (float*)carve((size_t)NN * HEADS * 4);
    float* alpha = (float*)carve((size_t)NET * HEADS * 4);
    float* einv  = (float*)carve((size_t)NN * HEADS * 4);
    int* counts = (int*)carve((size_t)NN * 4);
    int* cursor = (int*)carve((size_t)NN * 4);
    int* indptr = (int*)carve((size_t)(NN + 1) * 4);
    int* csr_src= (int*)carve((size_t)NET * 4);
    int* flag   = (int*)carve(4);
    (void)ws_size; (void)in_sizes; (void)n_in; (void)out_size;

    // CSR build (dtype-agnostic edge loads)
    init_kernel<<<(NN + 255) / 256, 256, 0, stream>>>((const int*)ei, flag, counts, cursor);
    count_kernel<<<(NET + 255) / 256, 256, 0, stream>>>(ei, flag, counts);
    scan_kernel<<<1, 256, 0, stream>>>(counts, indptr);
    fill_kernel<<<(NET + 255) / 256, 256, 0, stream>>>(ei, flag, indptr, cursor, csr_src);

    // fused conversions (cvt + 3 transposes)
    prep_kernel<<<CVT_NB + TP1_NB + TP2_NB + TP3_NB, 256, 0, stream>>>(
        x, xb, W1, W1t, W2, W2t, fcW, fcWt);

    const int MB = (NN + BM - 1) / BM;  // 79
    // layer 1
    gemm128<<<MB * (D1 / BN), 256, 0, stream>>>(xb, W1t, nullptr, nullptr, hb,
                                                NN, D1, IN_DIM, D1 / BN);
    att_kernel<<<NN / 4, 256, 0, stream>>>(hb, as1, ad1, aS, aD);
    alpha_kernel<<<NN / 4, 256, 0, stream>>>(aS, aD, indptr, csr_src, alpha, einv);
    agg_kernel<<<(NN / 4) * 8, 256, 0, stream>>>(hb, alpha, einv, indptr, csr_src, b1, x2b);
    // layer 2
    gemm128<<<MB * (D1 / BN), 256, 0, stream>>>(x2b, W2t, nullptr, nullptr, hb,
                                                NN, D1, D1, D1 / BN);
    att_kernel<<<NN / 4, 256, 0, stream>>>(hb, as2, ad2, aS, aD);
    alpha_kernel<<<NN / 4, 256, 0, stream>>>(aS, aD, indptr, csr_src, alpha, einv);
    agg_kernel<<<(NN / 4) * 8, 256, 0, stream>>>(hb, alpha, einv, indptr, csr_src, b2, x2b);
    // final fc (bias, f32 out)
    gemm128<<<MB * (OUT_DIM / BN), 256, 0, stream>>>(x2b, fcWt, fcb, out, nullptr,
                                                     NN, OUT_DIM, D1, OUT_DIM / BN);
}